// Round 15
// baseline (489.292 us; speedup 1.0000x reference)
//
#include <hip/hip_runtime.h>
#include <hip/hip_bf16.h>

#define N_NODES 50000
#define N_EDGES 800000
#define H 64
#define ED 32
#define LAYERS 3
#define NGRAPH 256
#define OUTD 32
#define SCALE 0.125f
#define SCAN_NB ((N_NODES + 255) / 256)   // 196

// fused front-end block ranges (h is bf16: N_NODES*32 words)
#define NB_INIT 6250
#define NB_TE   8
#define NB_HIST 3125
#define NB_GB   2
#define NB_FRONT (NB_INIT + NB_TE + NB_HIST + NB_GB)
#define NB_GEMM ((N_NODES + 63) / 64)     // 782

typedef __attribute__((ext_vector_type(16))) float f16v;
typedef __attribute__((ext_vector_type(16))) unsigned u16vec;
typedef unsigned short ushort_t;

// fp32 -> bf16 round-to-nearest-even
__device__ __forceinline__ unsigned f2bf(float f) {
    unsigned u = __float_as_uint(f);
    return (u + 0x7FFFu + ((u >> 16) & 1u)) >> 16;
}

// issue two s_load_dwordx16 (one bf16 h row = 128B), no wait
#define SLOAD2(d0, d1, addr) \
    asm volatile("s_load_dwordx16 %0, %2, 0x0\n\ts_load_dwordx16 %1, %2, 0x40" \
                 : "=&s"(d0), "=&s"(d1) : "s"(addr));
// wait for outstanding scalar loads; ties the regs to the wait
#define SWAIT2(d0, d1) asm volatile("s_waitcnt lgkmcnt(0)" : "+s"(d0), "+s"(d1));

// ---------------- fused front end: init_h(bf16) | te | hist | gbounds ----------------
__global__ __launch_bounds__(256) void k_front(
    const int* __restrict__ x, const float* __restrict__ node_emb, unsigned* __restrict__ h,
    const float* __restrict__ edge_emb, const float* __restrict__ We, float* __restrict__ te,
    const int* __restrict__ ei, int* __restrict__ deg,
    const int* __restrict__ batch, int* __restrict__ gs)
{
    int b = blockIdx.x, t = threadIdx.x;
    if (b < NB_INIT) {
        int i = b * 256 + t;              // word index: node = i>>5, word = i&31
        int n = i >> 5, w = i & 31;
        const float* src = node_emb + (size_t)x[n] * H + 2 * w;
        h[i] = f2bf(src[0]) | (f2bf(src[1]) << 16);
    } else if (b < NB_INIT + NB_TE) {
        int i = (b - NB_INIT) * 256 + t;
        if (i < LAYERS * 10 * H) {
            int c = i & 63;
            int cat = (i >> 6) % 10;
            int l = i / (10 * H);
            float acc = 0.f;
            for (int d = 0; d < ED; d++)
                acc += edge_emb[cat * ED + d] * We[((size_t)l * ED + d) * H + c];
            te[i] = acc;
        }
    } else if (b < NB_INIT + NB_TE + NB_HIST) {
        int e = (b - NB_INIT - NB_TE) * 256 + t;
        atomicAdd(&deg[ei[N_EDGES + e]], 1);
    } else {
        int g = (b - NB_INIT - NB_TE - NB_HIST) * 256 + t;
        if (g <= NGRAPH) {
            int lo = 0, hi = N_NODES;
            while (lo < hi) {
                int mid = (lo + hi) >> 1;
                if (batch[mid] < g) lo = mid + 1; else hi = mid;
            }
            gs[g] = lo;
        }
    }
}

// ---------------- scans ----------------
__global__ __launch_bounds__(256) void k_scan1(const int* __restrict__ deg, int* __restrict__ bsum) {
    __shared__ int red[256];
    int t = threadIdx.x;
    int i = blockIdx.x * 256 + t;
    red[t] = (i < N_NODES) ? deg[i] : 0;
    __syncthreads();
    for (int s = 128; s > 0; s >>= 1) {
        if (t < s) red[t] += red[t + s];
        __syncthreads();
    }
    if (t == 0) bsum[blockIdx.x] = red[0];
}

__global__ __launch_bounds__(256) void k_scan23(const int* __restrict__ deg, const int* __restrict__ bsum,
                                                int* __restrict__ row_start, int* __restrict__ cursor) {
    __shared__ int part[256];
    int t = threadIdx.x;
    part[t] = (t < SCAN_NB) ? bsum[t] : 0;
    __syncthreads();
    for (int off = 1; off < 256; off <<= 1) {
        int add = (t >= off) ? part[t - off] : 0;
        __syncthreads();
        part[t] += add;
        __syncthreads();
    }
    int boff = (blockIdx.x == 0) ? 0 : part[blockIdx.x - 1];
    __syncthreads();
    int i = blockIdx.x * 256 + t;
    int v = (i < N_NODES) ? deg[i] : 0;
    part[t] = v;
    __syncthreads();
    for (int off = 1; off < 256; off <<= 1) {
        int add = (t >= off) ? part[t - off] : 0;
        __syncthreads();
        part[t] += add;
        __syncthreads();
    }
    if (i < N_NODES) {
        int excl = part[t] - v + boff;
        row_start[i] = excl;
        cursor[i] = excl;
    }
}

// unpacked-bf16 dot: row (2x16 dwords) x weight col (4x16 floats)
__device__ __forceinline__ float dot_row(const u16vec& r0, const u16vec& r1,
                                         const f16v& w0, const f16v& w1,
                                         const f16v& w2, const f16v& w3, float bias)
{
    float acc = bias;
    #pragma unroll
    for (int i = 0; i < 8; i++) {
        acc = fmaf(__uint_as_float(r0[i] << 16),         w0[2 * i],     acc);
        acc = fmaf(__uint_as_float(r0[i] & 0xFFFF0000u), w0[2 * i + 1], acc);
    }
    #pragma unroll
    for (int i = 0; i < 8; i++) {
        acc = fmaf(__uint_as_float(r0[8 + i] << 16),         w1[2 * i],     acc);
        acc = fmaf(__uint_as_float(r0[8 + i] & 0xFFFF0000u), w1[2 * i + 1], acc);
    }
    #pragma unroll
    for (int i = 0; i < 8; i++) {
        acc = fmaf(__uint_as_float(r1[i] << 16),         w2[2 * i],     acc);
        acc = fmaf(__uint_as_float(r1[i] & 0xFFFF0000u), w2[2 * i + 1], acc);
    }
    #pragma unroll
    for (int i = 0; i < 8; i++) {
        acc = fmaf(__uint_as_float(r1[8 + i] << 16),         w3[2 * i],     acc);
        acc = fmaf(__uint_as_float(r1[8 + i] & 0xFFFF0000u), w3[2 * i + 1], acc);
    }
    return acc;
}

// ---------------- gemm body: wave = matrix, lane = col; double-buffered bf16 h rows ----
__device__ __forceinline__ void gemm_store(int wvi, int lane, int n, float acc,
                                           float* __restrict__ qs, unsigned* __restrict__ kv32)
{
    if (wvi == 0)      qs[(size_t)n * 128 + lane] = acc;
    else if (wvi == 3) qs[(size_t)n * 128 + 64 + lane] = acc;
    else if (wvi == 1) ((ushort_t*)kv32)[(((size_t)n << 6) + lane) * 2 + 1] = (ushort_t)f2bf(acc);
    else               ((ushort_t*)kv32)[(((size_t)n << 6) + lane) * 2 + 0] = (ushort_t)f2bf(acc);
}

__device__ __forceinline__ void gemm_body(
    int bid, const unsigned* __restrict__ h,
    const float* __restrict__ Wq, const float* __restrict__ Wk,
    const float* __restrict__ Wv, const float* __restrict__ Wsk,
    const float* __restrict__ bq, const float* __restrict__ bk,
    const float* __restrict__ bv, const float* __restrict__ bsk,
    float* __restrict__ qs, unsigned* __restrict__ kv32)
{
    int wvi = threadIdx.x >> 6, lane = threadIdx.x & 63;
    const float* Wm = (wvi == 0) ? Wq : (wvi == 1) ? Wk : (wvi == 2) ? Wv : Wsk;
    const float* bm = (wvi == 0) ? bq : (wvi == 1) ? bk : (wvi == 2) ? bv : bsk;
    f16v w0, w1, w2, w3;
    #pragma unroll
    for (int i = 0; i < 16; i++) w0[i] = Wm[i * H + lane];
    #pragma unroll
    for (int i = 0; i < 16; i++) w1[i] = Wm[(16 + i) * H + lane];
    #pragma unroll
    for (int i = 0; i < 16; i++) w2[i] = Wm[(32 + i) * H + lane];
    #pragma unroll
    for (int i = 0; i < 16; i++) w3[i] = Wm[(48 + i) * H + lane];
    float bias = bm[lane];
    int base = bid * 64;
    int nEnd = min(base + 64, N_NODES);
    u16vec A0, A1, B0, B1;
    const unsigned* r = h + (size_t)base * 32;
    SLOAD2(A0, A1, r);
    for (int n = base; n < nEnd; n += 2) {
        const unsigned* r1p = h + (size_t)min(n + 1, nEnd - 1) * 32;
        SWAIT2(A0, A1);
        SLOAD2(B0, B1, r1p);
        float acc = dot_row(A0, A1, w0, w1, w2, w3, bias);
        gemm_store(wvi, lane, n, acc, qs, kv32);
        if (n + 1 < nEnd) {
            const unsigned* r2p = h + (size_t)min(n + 2, nEnd - 1) * 32;
            SWAIT2(B0, B1);
            SLOAD2(A0, A1, r2p);
            float acc2 = dot_row(B0, B1, w0, w1, w2, w3, bias);
            gemm_store(wvi, lane, n + 1, acc2, qs, kv32);
        }
    }
}

// layers 1,2: plain gemm
__global__ __launch_bounds__(256, 1) void k_gemm(
    const unsigned* __restrict__ h,
    const float* __restrict__ Wq, const float* __restrict__ Wk,
    const float* __restrict__ Wv, const float* __restrict__ Wsk,
    const float* __restrict__ bq, const float* __restrict__ bk,
    const float* __restrict__ bv, const float* __restrict__ bsk,
    float* __restrict__ qs, unsigned* __restrict__ kv32)
{
    gemm_body(blockIdx.x, h, Wq, Wk, Wv, Wsk, bq, bk, bv, bsk, qs, kv32);
}

// layer 0: gemm blocks [0,NB_GEMM), scatter blocks [NB_GEMM, NB_GEMM+NB_HIST)
__global__ __launch_bounds__(256, 1) void k_gemm_scatter(
    const unsigned* __restrict__ h,
    const float* __restrict__ Wq, const float* __restrict__ Wk,
    const float* __restrict__ Wv, const float* __restrict__ Wsk,
    const float* __restrict__ bq, const float* __restrict__ bk,
    const float* __restrict__ bv, const float* __restrict__ bsk,
    float* __restrict__ qs, unsigned* __restrict__ kv32,
    const int* __restrict__ ei, const int* __restrict__ ea,
    int* __restrict__ cursor, int* __restrict__ packed)
{
    int b = blockIdx.x;
    if (b < NB_GEMM) {
        gemm_body(b, h, Wq, Wk, Wv, Wsk, bq, bk, bv, bsk, qs, kv32);
    } else {
        int e = (b - NB_GEMM) * 256 + threadIdx.x;
        int src = ei[e], dst = ei[N_EDGES + e], cat = ea[e];
        int pos = atomicAdd(&cursor[dst], 1);
        packed[pos] = src | (cat << 16);
    }
}

// per-edge load bundle
struct EdgeLd { uint4 kv; float4 t; };
__device__ __forceinline__ EdgeLd edge_load(int pkt, const unsigned* __restrict__ kv32,
                                            const float* tel, int i16) {
    EdgeLd r;
    r.kv = *(const uint4*)(kv32 + ((size_t)(pkt & 0xFFFF) << 6) + (i16 << 2));
    r.t  = *(const float4*)(tel + ((pkt >> 16) << 6) + (i16 << 2));
    return r;
}
__device__ __forceinline__ float edge_dot(const EdgeLd& e, const float4& q4) {
    float p;
    p = (__uint_as_float(e.kv.x & 0xFFFF0000u) + e.t.x) * q4.x;
    p = fmaf(__uint_as_float(e.kv.y & 0xFFFF0000u) + e.t.y, q4.y, p);
    p = fmaf(__uint_as_float(e.kv.z & 0xFFFF0000u) + e.t.z, q4.z, p);
    p = fmaf(__uint_as_float(e.kv.w & 0xFFFF0000u) + e.t.w, q4.w, p);
    p += __shfl_xor(p, 1); p += __shfl_xor(p, 2);
    p += __shfl_xor(p, 4); p += __shfl_xor(p, 8);
    return p * SCALE;
}
__device__ __forceinline__ float4 edge_val(const EdgeLd& e) {
    float4 v;
    v.x = __uint_as_float(e.kv.x << 16) + e.t.x;
    v.y = __uint_as_float(e.kv.y << 16) + e.t.y;
    v.z = __uint_as_float(e.kv.z << 16) + e.t.z;
    v.w = __uint_as_float(e.kv.w << 16) + e.t.w;
    return v;
}

// ---------------- fused gather: 4x16 lane-split + 4-deep unroll; bf16 h out ----------------
__global__ __launch_bounds__(256) void k_agg(
    const int* __restrict__ row_start, const int* __restrict__ row_end,
    const int* __restrict__ packed,
    const float* __restrict__ qs, const unsigned* __restrict__ kv32,
    const float* __restrict__ te, unsigned* __restrict__ h,
    const float* __restrict__ gW, const float* __restrict__ gb, float* __restrict__ gate)
{
    __shared__ float tel[10 * 64];
    for (int i = threadIdx.x; i < 10 * 64; i += 256) tel[i] = te[i];
    __syncthreads();
    int wave = threadIdx.x >> 6, lane = threadIdx.x & 63;
    int g = lane >> 4, i16 = lane & 15;
    int dst = blockIdx.x * 4 + wave;
    if (dst >= N_NODES) return;
    int beg = row_start[dst], end = row_end[dst];
    float4 q4 = *(const float4*)(qs + (size_t)dst * 128 + (i16 << 2));
    float m = -1e30f, l = 0.f;
    float4 acc = {0.f, 0.f, 0.f, 0.f};
    int e = beg + g;
    for (; e + 12 < end; e += 16) {
        int p0 = packed[e], p1 = packed[e + 4], p2 = packed[e + 8], p3 = packed[e + 12];
        EdgeLd e0 = edge_load(p0, kv32, tel, i16);
        EdgeLd e1 = edge_load(p1, kv32, tel, i16);
        EdgeLd e2 = edge_load(p2, kv32, tel, i16);
        EdgeLd e3 = edge_load(p3, kv32, tel, i16);
        float a0 = edge_dot(e0, q4), a1 = edge_dot(e1, q4);
        float a2 = edge_dot(e2, q4), a3 = edge_dot(e3, q4);
        float mn = fmaxf(m, fmaxf(fmaxf(a0, a1), fmaxf(a2, a3)));
        float corr = __expf(m - mn);
        float w0 = __expf(a0 - mn), w1 = __expf(a1 - mn);
        float w2 = __expf(a2 - mn), w3 = __expf(a3 - mn);
        float4 v0 = edge_val(e0), v1 = edge_val(e1), v2 = edge_val(e2), v3 = edge_val(e3);
        acc.x = fmaf(w0, v0.x, fmaf(w1, v1.x, fmaf(w2, v2.x, fmaf(w3, v3.x, acc.x * corr))));
        acc.y = fmaf(w0, v0.y, fmaf(w1, v1.y, fmaf(w2, v2.y, fmaf(w3, v3.y, acc.y * corr))));
        acc.z = fmaf(w0, v0.z, fmaf(w1, v1.z, fmaf(w2, v2.z, fmaf(w3, v3.z, acc.z * corr))));
        acc.w = fmaf(w0, v0.w, fmaf(w1, v1.w, fmaf(w2, v2.w, fmaf(w3, v3.w, acc.w * corr))));
        l = fmaf(l, corr, (w0 + w1) + (w2 + w3));
        m = mn;
    }
    for (; e < end; e += 4) {
        int pkt = packed[e];
        EdgeLd e0 = edge_load(pkt, kv32, tel, i16);
        float a = edge_dot(e0, q4);
        float mn = fmaxf(m, a);
        float corr = __expf(m - mn);
        float w = __expf(a - mn);
        float4 v4 = edge_val(e0);
        acc.x = fmaf(w, v4.x, acc.x * corr);
        acc.y = fmaf(w, v4.y, acc.y * corr);
        acc.z = fmaf(w, v4.z, acc.z * corr);
        acc.w = fmaf(w, v4.w, acc.w * corr);
        l = fmaf(l, corr, w);
        m = mn;
    }
    float M = fmaxf(m, __shfl_xor(m, 16));
    M = fmaxf(M, __shfl_xor(M, 32));
    float sc = __expf(m - M);
    l *= sc;
    acc.x *= sc; acc.y *= sc; acc.z *= sc; acc.w *= sc;
    l += __shfl_xor(l, 16); l += __shfl_xor(l, 32);
    acc.x += __shfl_xor(acc.x, 16); acc.x += __shfl_xor(acc.x, 32);
    acc.y += __shfl_xor(acc.y, 16); acc.y += __shfl_xor(acc.y, 32);
    acc.z += __shfl_xor(acc.z, 16); acc.z += __shfl_xor(acc.z, 32);
    acc.w += __shfl_xor(acc.w, 16); acc.w += __shfl_xor(acc.w, 32);
    float inv = (l > 0.f) ? 1.f / l : 0.f;
    float4 s4 = *(const float4*)(qs + (size_t)dst * 128 + 64 + (i16 << 2));
    float4 hv;
    hv.x = fmaxf(acc.x * inv + s4.x, 0.f);
    hv.y = fmaxf(acc.y * inv + s4.y, 0.f);
    hv.z = fmaxf(acc.z * inv + s4.z, 0.f);
    hv.w = fmaxf(acc.w * inv + s4.w, 0.f);
    if (g == 0) {
        uint2 pk;
        pk.x = f2bf(hv.x) | (f2bf(hv.y) << 16);
        pk.y = f2bf(hv.z) | (f2bf(hv.w) << 16);
        *(uint2*)(h + (size_t)dst * 32 + (i16 << 1)) = pk;
    }
    if (gW) {
        float4 g4 = *(const float4*)(gW + (i16 << 2));
        float p = hv.x * g4.x + hv.y * g4.y + hv.z * g4.z + hv.w * g4.w;
        p += __shfl_xor(p, 1); p += __shfl_xor(p, 2);
        p += __shfl_xor(p, 4); p += __shfl_xor(p, 8);
        if (lane == 0) gate[dst] = p + gb[0];
    }
}

// ---------------- fused per-graph readout (bf16 h in) ----------------
__global__ __launch_bounds__(256) void k_readout2(
    const unsigned* __restrict__ h, const float* __restrict__ oW,
    const float* __restrict__ ob, const float* __restrict__ gate,
    const int* __restrict__ gs, float* __restrict__ out)
{
    __shared__ float wls[H * OUTD];
    __shared__ float hs[8][H + 1];
    __shared__ float red[256];
    __shared__ float den_s[8];
    __shared__ float gmax_s, den_tot;
    int t = threadIdx.x;
    int g = blockIdx.x;
    for (int i = t; i < H * OUTD; i += 256) wls[i] = oW[i];
    int beg = gs[g], end = gs[g + 1];
    float mx = -INFINITY;
    for (int n = beg + t; n < end; n += 256) mx = fmaxf(mx, gate[n]);
    red[t] = mx;
    __syncthreads();
    for (int sft = 128; sft > 0; sft >>= 1) {
        if (t < sft) red[t] = fmaxf(red[t], red[t + sft]);
        __syncthreads();
    }
    if (t == 0) gmax_s = red[0];
    __syncthreads();
    float gm = gmax_s;
    int ln = t >> 5, o = t & 31;
    float acc = 0.f, den = 0.f;
    for (int n0 = beg; n0 < end; n0 += 8) {
        __syncthreads();
        {
            int i = t;            // 256 threads, 8 rows x 32 words
            int r = i >> 5, wd = i & 31;
            int n = n0 + r;
            unsigned wv = (n < end) ? h[(size_t)n * 32 + wd] : 0u;
            hs[r][2 * wd]     = __uint_as_float(wv << 16);
            hs[r][2 * wd + 1] = __uint_as_float(wv & 0xFFFF0000u);
        }
        __syncthreads();
        int n = n0 + ln;
        if (n < end) {
            float wt = __expf(gate[n] - gm);
            float d0 = 0.f;
            #pragma unroll
            for (int i = 0; i < H; i++) d0 += hs[ln][i] * wls[i * OUTD + o];
            acc += wt * d0;
            if (o == 0) den += wt;
        }
    }
    __syncthreads();
    red[t] = acc;
    if (o == 0) den_s[ln] = den;
    __syncthreads();
    for (int sft = 4; sft >= 1; sft >>= 1) {
        if (ln < sft) red[t] += red[t + sft * 32];
        __syncthreads();
    }
    if (t == 0) {
        float dt = 0.f;
        #pragma unroll
        for (int i = 0; i < 8; i++) dt += den_s[i];
        den_tot = dt;
    }
    __syncthreads();
    if (ln == 0) {
        float dt = den_tot;
        out[g * OUTD + o] = (dt > 0.f) ? red[o] / dt + ob[o] : 0.f;
    }
}

extern "C" void kernel_launch(void* const* d_in, const int* in_sizes, int n_in,
                              void* d_out, int out_size, void* d_ws, size_t ws_size,
                              hipStream_t stream)
{
    const int* x        = (const int*)d_in[0];
    const int* ei       = (const int*)d_in[1];
    const int* ea       = (const int*)d_in[2];
    const int* batch    = (const int*)d_in[3];
    const float* node_emb = (const float*)d_in[4];
    const float* edge_emb = (const float*)d_in[5];
    const float* Wq    = (const float*)d_in[6];
    const float* Wk    = (const float*)d_in[7];
    const float* Wv    = (const float*)d_in[8];
    const float* We    = (const float*)d_in[9];
    const float* Wskip = (const float*)d_in[10];
    const float* bq    = (const float*)d_in[11];
    const float* bk    = (const float*)d_in[12];
    const float* bv    = (const float*)d_in[13];
    const float* bskip = (const float*)d_in[14];
    const float* gate_W = (const float*)d_in[15];
    const float* gate_b = (const float*)d_in[16];
    const float* out_W  = (const float*)d_in[17];
    const float* out_b  = (const float*)d_in[18];
    float* out = (float*)d_out;

    const size_t NH = (size_t)N_NODES * H;
    float* ws   = (float*)d_ws;
    unsigned* h = (unsigned*)ws;             // bf16 h, 32 words/node (NH/2 floats of space)
    float* qs   = ws + NH / 2;               // fp32 [q(64)|s(64)] per node
    unsigned* kv32 = (unsigned*)(qs + 2 * NH); // packed bf16 k|v, 64 uints/node
    float* te   = (float*)(kv32 + NH);
    float* gate = te + LAYERS * 10 * H;
    int* deg       = (int*)(gate + N_NODES);
    int* row_start = deg + N_NODES;
    int* cursor    = row_start + N_NODES;
    int* packed    = cursor + N_NODES;
    int* gs        = packed + N_EDGES;   // 257 ints
    int* bsum      = gs + NGRAPH + 1;    // 196

    hipMemsetAsync(deg, 0, N_NODES * sizeof(int), stream);

    k_front<<<NB_FRONT, 256, 0, stream>>>(x, node_emb, h, edge_emb, We, te, ei, deg, batch, gs);
    k_scan1<<<SCAN_NB, 256, 0, stream>>>(deg, bsum);
    k_scan23<<<SCAN_NB, 256, 0, stream>>>(deg, bsum, row_start, cursor);

    // layer 0: gemm fused with scatter (independent work, co-scheduled)
    k_gemm_scatter<<<NB_GEMM + NB_HIST, 256, 0, stream>>>(
        h, Wq, Wk, Wv, Wskip, bq, bk, bv, bskip, qs, kv32, ei, ea, cursor, packed);
    k_agg<<<(N_NODES + 3) / 4, 256, 0, stream>>>(
        row_start, cursor, packed, qs, kv32, te, h, nullptr, nullptr, nullptr);

    for (int l = 1; l < LAYERS; l++) {
        k_gemm<<<NB_GEMM, 256, 0, stream>>>(
            h,
            Wq + (size_t)l * H * H, Wk + (size_t)l * H * H,
            Wv + (size_t)l * H * H, Wskip + (size_t)l * H * H,
            bq + (size_t)l * H, bk + (size_t)l * H, bv + (size_t)l * H, bskip + (size_t)l * H,
            qs, kv32);
        const float* gw = (l == LAYERS - 1) ? gate_W : nullptr;
        const float* gb = (l == LAYERS - 1) ? gate_b : nullptr;
        float* gp       = (l == LAYERS - 1) ? gate : nullptr;
        k_agg<<<(N_NODES + 3) / 4, 256, 0, stream>>>(
            row_start, cursor, packed, qs, kv32, te + (size_t)l * 10 * H, h, gw, gb, gp);
    }

    k_readout2<<<NGRAPH, 256, 0, stream>>>(h, out_W, out_b, gate, gs, out);
}

// Round 16
// 479.013 us; speedup vs baseline: 1.0215x; 1.0215x over previous
//
#include <hip/hip_runtime.h>
#include <hip/hip_bf16.h>

#define N_NODES 50000
#define N_EDGES 800000
#define H 64
#define ED 32
#define LAYERS 3
#define NGRAPH 256
#define OUTD 32
#define SCALE 0.125f
#define SCAN_NB ((N_NODES + 255) / 256)   // 196

// fused front-end block ranges
#define NB_INIT 12500
#define NB_TE   8
#define NB_HIST 3125
#define NB_GB   2
#define NB_FRONT (NB_INIT + NB_TE + NB_HIST + NB_GB)
#define NB_GEMM ((N_NODES + 63) / 64)     // 782

typedef __attribute__((ext_vector_type(16))) float f16v;
typedef unsigned short ushort_t;

// fp32 -> bf16 round-to-nearest-even
__device__ __forceinline__ unsigned f2bf(float f) {
    unsigned u = __float_as_uint(f);
    return (u + 0x7FFFu + ((u >> 16) & 1u)) >> 16;
}

// ---------------- fused front end: init_h | te | hist | gbounds ----------------
__global__ __launch_bounds__(256) void k_front(
    const int* __restrict__ x, const float* __restrict__ node_emb, float* __restrict__ h,
    const float* __restrict__ edge_emb, const float* __restrict__ We, float* __restrict__ te,
    const int* __restrict__ ei, int* __restrict__ deg,
    const int* __restrict__ batch, int* __restrict__ gs)
{
    int b = blockIdx.x, t = threadIdx.x;
    if (b < NB_INIT) {
        int i = b * 256 + t;
        int n = i >> 6, c = i & 63;
        h[i] = node_emb[x[n] * H + c];
    } else if (b < NB_INIT + NB_TE) {
        int i = (b - NB_INIT) * 256 + t;
        if (i < LAYERS * 10 * H) {
            int c = i & 63;
            int cat = (i >> 6) % 10;
            int l = i / (10 * H);
            float acc = 0.f;
            for (int d = 0; d < ED; d++)
                acc += edge_emb[cat * ED + d] * We[((size_t)l * ED + d) * H + c];
            te[i] = acc;
        }
    } else if (b < NB_INIT + NB_TE + NB_HIST) {
        int e = (b - NB_INIT - NB_TE) * 256 + t;
        atomicAdd(&deg[ei[N_EDGES + e]], 1);
    } else {
        int g = (b - NB_INIT - NB_TE - NB_HIST) * 256 + t;
        if (g <= NGRAPH) {
            int lo = 0, hi = N_NODES;
            while (lo < hi) {
                int mid = (lo + hi) >> 1;
                if (batch[mid] < g) lo = mid + 1; else hi = mid;
            }
            gs[g] = lo;
        }
    }
}

// ---------------- scans ----------------
__global__ __launch_bounds__(256) void k_scan1(const int* __restrict__ deg, int* __restrict__ bsum) {
    __shared__ int red[256];
    int t = threadIdx.x;
    int i = blockIdx.x * 256 + t;
    red[t] = (i < N_NODES) ? deg[i] : 0;
    __syncthreads();
    for (int s = 128; s > 0; s >>= 1) {
        if (t < s) red[t] += red[t + s];
        __syncthreads();
    }
    if (t == 0) bsum[blockIdx.x] = red[0];
}

__global__ __launch_bounds__(256) void k_scan23(const int* __restrict__ deg, const int* __restrict__ bsum,
                                                int* __restrict__ row_start, int* __restrict__ cursor) {
    __shared__ int part[256];
    int t = threadIdx.x;
    part[t] = (t < SCAN_NB) ? bsum[t] : 0;
    __syncthreads();
    for (int off = 1; off < 256; off <<= 1) {
        int add = (t >= off) ? part[t - off] : 0;
        __syncthreads();
        part[t] += add;
        __syncthreads();
    }
    int boff = (blockIdx.x == 0) ? 0 : part[blockIdx.x - 1];
    __syncthreads();
    int i = blockIdx.x * 256 + t;
    int v = (i < N_NODES) ? deg[i] : 0;
    part[t] = v;
    __syncthreads();
    for (int off = 1; off < 256; off <<= 1) {
        int add = (t >= off) ? part[t - off] : 0;
        __syncthreads();
        part[t] += add;
        __syncthreads();
    }
    if (i < N_NODES) {
        int excl = part[t] - v + boff;
        row_start[i] = excl;
        cursor[i] = excl;
    }
}

// ---------------- gemm body: wave = matrix, lane = col (fp32 h via s_load) ----------------
// q -> bf16 qs16[n][0:64); s -> bf16 qs16[n][64:128); k,v -> one uint (k hi16, v lo16)
__device__ __forceinline__ void gemm_store(int wvi, int lane, int n, float acc,
                                           ushort_t* __restrict__ qs16, unsigned* __restrict__ kv32)
{
    if (wvi == 0)      qs16[(size_t)n * 128 + lane] = (ushort_t)f2bf(acc);
    else if (wvi == 3) qs16[(size_t)n * 128 + 64 + lane] = (ushort_t)f2bf(acc);
    else if (wvi == 1) ((ushort_t*)kv32)[(((size_t)n << 6) + lane) * 2 + 1] = (ushort_t)f2bf(acc);
    else               ((ushort_t*)kv32)[(((size_t)n << 6) + lane) * 2 + 0] = (ushort_t)f2bf(acc);
}

__device__ __forceinline__ void gemm_body(
    int bid, const float* __restrict__ h,
    const float* __restrict__ Wq, const float* __restrict__ Wk,
    const float* __restrict__ Wv, const float* __restrict__ Wsk,
    const float* __restrict__ bq, const float* __restrict__ bk,
    const float* __restrict__ bv, const float* __restrict__ bsk,
    ushort_t* __restrict__ qs16, unsigned* __restrict__ kv32)
{
    int wvi = threadIdx.x >> 6, lane = threadIdx.x & 63;
    const float* Wm = (wvi == 0) ? Wq : (wvi == 1) ? Wk : (wvi == 2) ? Wv : Wsk;
    const float* bm = (wvi == 0) ? bq : (wvi == 1) ? bk : (wvi == 2) ? bv : bsk;
    f16v w0, w1, w2, w3;
    #pragma unroll
    for (int i = 0; i < 16; i++) w0[i] = Wm[i * H + lane];
    #pragma unroll
    for (int i = 0; i < 16; i++) w1[i] = Wm[(16 + i) * H + lane];
    #pragma unroll
    for (int i = 0; i < 16; i++) w2[i] = Wm[(32 + i) * H + lane];
    #pragma unroll
    for (int i = 0; i < 16; i++) w3[i] = Wm[(48 + i) * H + lane];
    float bias = bm[lane];
    int base = bid * 64;
    int nEnd = min(base + 64, N_NODES);
    for (int n = base; n < nEnd; n++) {
        const float* hrow = h + (size_t)n * H;
        f16v h0, h1, h2, h3;
        asm volatile(
            "s_load_dwordx16 %0, %4, 0x0\n\t"
            "s_load_dwordx16 %1, %4, 0x40\n\t"
            "s_load_dwordx16 %2, %4, 0x80\n\t"
            "s_load_dwordx16 %3, %4, 0xc0\n\t"
            "s_waitcnt lgkmcnt(0)"
            : "=s"(h0), "=s"(h1), "=s"(h2), "=s"(h3)
            : "s"(hrow));
        float acc = bias;
        #pragma unroll
        for (int i = 0; i < 16; i++) acc = fmaf(h0[i], w0[i], acc);
        #pragma unroll
        for (int i = 0; i < 16; i++) acc = fmaf(h1[i], w1[i], acc);
        #pragma unroll
        for (int i = 0; i < 16; i++) acc = fmaf(h2[i], w2[i], acc);
        #pragma unroll
        for (int i = 0; i < 16; i++) acc = fmaf(h3[i], w3[i], acc);
        gemm_store(wvi, lane, n, acc, qs16, kv32);
    }
}

// layers 1,2: plain gemm
__global__ __launch_bounds__(256, 1) void k_gemm(
    const float* __restrict__ h,
    const float* __restrict__ Wq, const float* __restrict__ Wk,
    const float* __restrict__ Wv, const float* __restrict__ Wsk,
    const float* __restrict__ bq, const float* __restrict__ bk,
    const float* __restrict__ bv, const float* __restrict__ bsk,
    ushort_t* __restrict__ qs16, unsigned* __restrict__ kv32)
{
    gemm_body(blockIdx.x, h, Wq, Wk, Wv, Wsk, bq, bk, bv, bsk, qs16, kv32);
}

// layer 0: gemm blocks [0,NB_GEMM), scatter blocks [NB_GEMM, NB_GEMM+NB_HIST)
__global__ __launch_bounds__(256, 1) void k_gemm_scatter(
    const float* __restrict__ h,
    const float* __restrict__ Wq, const float* __restrict__ Wk,
    const float* __restrict__ Wv, const float* __restrict__ Wsk,
    const float* __restrict__ bq, const float* __restrict__ bk,
    const float* __restrict__ bv, const float* __restrict__ bsk,
    ushort_t* __restrict__ qs16, unsigned* __restrict__ kv32,
    const int* __restrict__ ei, const int* __restrict__ ea,
    int* __restrict__ cursor, int* __restrict__ packed)
{
    int b = blockIdx.x;
    if (b < NB_GEMM) {
        gemm_body(b, h, Wq, Wk, Wv, Wsk, bq, bk, bv, bsk, qs16, kv32);
    } else {
        int e = (b - NB_GEMM) * 256 + threadIdx.x;
        int src = ei[e], dst = ei[N_EDGES + e], cat = ea[e];
        int pos = atomicAdd(&cursor[dst], 1);
        packed[pos] = src | (cat << 16);
    }
}

// per-edge load bundle
struct EdgeLd { uint4 kv; float4 t; };
__device__ __forceinline__ EdgeLd edge_load(int pkt, const unsigned* __restrict__ kv32,
                                            const float* tel, int i16) {
    EdgeLd r;
    r.kv = *(const uint4*)(kv32 + ((size_t)(pkt & 0xFFFF) << 6) + (i16 << 2));
    r.t  = *(const float4*)(tel + ((pkt >> 16) << 6) + (i16 << 2));
    return r;
}
__device__ __forceinline__ float edge_dot(const EdgeLd& e, const float4& q4) {
    float p;
    p = (__uint_as_float(e.kv.x & 0xFFFF0000u) + e.t.x) * q4.x;
    p = fmaf(__uint_as_float(e.kv.y & 0xFFFF0000u) + e.t.y, q4.y, p);
    p = fmaf(__uint_as_float(e.kv.z & 0xFFFF0000u) + e.t.z, q4.z, p);
    p = fmaf(__uint_as_float(e.kv.w & 0xFFFF0000u) + e.t.w, q4.w, p);
    p += __shfl_xor(p, 1); p += __shfl_xor(p, 2);
    p += __shfl_xor(p, 4); p += __shfl_xor(p, 8);
    return p * SCALE;
}
__device__ __forceinline__ float4 edge_val(const EdgeLd& e) {
    float4 v;
    v.x = __uint_as_float(e.kv.x << 16) + e.t.x;
    v.y = __uint_as_float(e.kv.y << 16) + e.t.y;
    v.z = __uint_as_float(e.kv.z << 16) + e.t.z;
    v.w = __uint_as_float(e.kv.w << 16) + e.t.w;
    return v;
}

// ---------------- fused gather: 4x16 lane-split + 4-deep unroll; bf16 q/s in ----------------
__global__ __launch_bounds__(256) void k_agg(
    const int* __restrict__ row_start, const int* __restrict__ row_end,
    const int* __restrict__ packed,
    const ushort_t* __restrict__ qs16, const unsigned* __restrict__ kv32,
    const float* __restrict__ te, float* __restrict__ h,
    const float* __restrict__ gW, const float* __restrict__ gb, float* __restrict__ gate)
{
    __shared__ float tel[10 * 64];
    for (int i = threadIdx.x; i < 10 * 64; i += 256) tel[i] = te[i];
    __syncthreads();
    int wave = threadIdx.x >> 6, lane = threadIdx.x & 63;
    int g = lane >> 4, i16 = lane & 15;
    int dst = blockIdx.x * 4 + wave;
    if (dst >= N_NODES) return;
    int beg = row_start[dst], end = row_end[dst];
    // unpack bf16 q (4 channels/lane), once per dst
    uint2 qw = *(const uint2*)(qs16 + (size_t)dst * 128 + (i16 << 2));
    float4 q4;
    q4.x = __uint_as_float(qw.x << 16);
    q4.y = __uint_as_float(qw.x & 0xFFFF0000u);
    q4.z = __uint_as_float(qw.y << 16);
    q4.w = __uint_as_float(qw.y & 0xFFFF0000u);
    float m = -1e30f, l = 0.f;
    float4 acc = {0.f, 0.f, 0.f, 0.f};
    int e = beg + g;
    for (; e + 12 < end; e += 16) {
        int p0 = packed[e], p1 = packed[e + 4], p2 = packed[e + 8], p3 = packed[e + 12];
        EdgeLd e0 = edge_load(p0, kv32, tel, i16);
        EdgeLd e1 = edge_load(p1, kv32, tel, i16);
        EdgeLd e2 = edge_load(p2, kv32, tel, i16);
        EdgeLd e3 = edge_load(p3, kv32, tel, i16);
        float a0 = edge_dot(e0, q4), a1 = edge_dot(e1, q4);
        float a2 = edge_dot(e2, q4), a3 = edge_dot(e3, q4);
        float mn = fmaxf(m, fmaxf(fmaxf(a0, a1), fmaxf(a2, a3)));
        float corr = __expf(m - mn);
        float w0 = __expf(a0 - mn), w1 = __expf(a1 - mn);
        float w2 = __expf(a2 - mn), w3 = __expf(a3 - mn);
        float4 v0 = edge_val(e0), v1 = edge_val(e1), v2 = edge_val(e2), v3 = edge_val(e3);
        acc.x = fmaf(w0, v0.x, fmaf(w1, v1.x, fmaf(w2, v2.x, fmaf(w3, v3.x, acc.x * corr))));
        acc.y = fmaf(w0, v0.y, fmaf(w1, v1.y, fmaf(w2, v2.y, fmaf(w3, v3.y, acc.y * corr))));
        acc.z = fmaf(w0, v0.z, fmaf(w1, v1.z, fmaf(w2, v2.z, fmaf(w3, v3.z, acc.z * corr))));
        acc.w = fmaf(w0, v0.w, fmaf(w1, v1.w, fmaf(w2, v2.w, fmaf(w3, v3.w, acc.w * corr))));
        l = fmaf(l, corr, (w0 + w1) + (w2 + w3));
        m = mn;
    }
    for (; e < end; e += 4) {
        int pkt = packed[e];
        EdgeLd e0 = edge_load(pkt, kv32, tel, i16);
        float a = edge_dot(e0, q4);
        float mn = fmaxf(m, a);
        float corr = __expf(m - mn);
        float w = __expf(a - mn);
        float4 v4 = edge_val(e0);
        acc.x = fmaf(w, v4.x, acc.x * corr);
        acc.y = fmaf(w, v4.y, acc.y * corr);
        acc.z = fmaf(w, v4.z, acc.z * corr);
        acc.w = fmaf(w, v4.w, acc.w * corr);
        l = fmaf(l, corr, w);
        m = mn;
    }
    float M = fmaxf(m, __shfl_xor(m, 16));
    M = fmaxf(M, __shfl_xor(M, 32));
    float sc = __expf(m - M);
    l *= sc;
    acc.x *= sc; acc.y *= sc; acc.z *= sc; acc.w *= sc;
    l += __shfl_xor(l, 16); l += __shfl_xor(l, 32);
    acc.x += __shfl_xor(acc.x, 16); acc.x += __shfl_xor(acc.x, 32);
    acc.y += __shfl_xor(acc.y, 16); acc.y += __shfl_xor(acc.y, 32);
    acc.z += __shfl_xor(acc.z, 16); acc.z += __shfl_xor(acc.z, 32);
    acc.w += __shfl_xor(acc.w, 16); acc.w += __shfl_xor(acc.w, 32);
    float inv = (l > 0.f) ? 1.f / l : 0.f;
    // unpack bf16 s
    uint2 sw = *(const uint2*)(qs16 + (size_t)dst * 128 + 64 + (i16 << 2));
    float4 s4;
    s4.x = __uint_as_float(sw.x << 16);
    s4.y = __uint_as_float(sw.x & 0xFFFF0000u);
    s4.z = __uint_as_float(sw.y << 16);
    s4.w = __uint_as_float(sw.y & 0xFFFF0000u);
    float4 hv;
    hv.x = fmaxf(acc.x * inv + s4.x, 0.f);
    hv.y = fmaxf(acc.y * inv + s4.y, 0.f);
    hv.z = fmaxf(acc.z * inv + s4.z, 0.f);
    hv.w = fmaxf(acc.w * inv + s4.w, 0.f);
    if (g == 0) *(float4*)(h + (size_t)dst * H + (i16 << 2)) = hv;
    if (gW) {   // fused readout gate (final layer only)
        float4 g4 = *(const float4*)(gW + (i16 << 2));
        float p = hv.x * g4.x + hv.y * g4.y + hv.z * g4.z + hv.w * g4.w;
        p += __shfl_xor(p, 1); p += __shfl_xor(p, 2);
        p += __shfl_xor(p, 4); p += __shfl_xor(p, 8);
        if (lane == 0) gate[dst] = p + gb[0];
    }
}

// ---------------- fused per-graph readout ----------------
__global__ __launch_bounds__(256) void k_readout2(
    const float* __restrict__ h, const float* __restrict__ oW,
    const float* __restrict__ ob, const float* __restrict__ gate,
    const int* __restrict__ gs, float* __restrict__ out)
{
    __shared__ float wls[H * OUTD];
    __shared__ float hs[8][H + 1];
    __shared__ float red[256];
    __shared__ float den_s[8];
    __shared__ float gmax_s, den_tot;
    int t = threadIdx.x;
    int g = blockIdx.x;
    for (int i = t; i < H * OUTD; i += 256) wls[i] = oW[i];
    int beg = gs[g], end = gs[g + 1];
    float mx = -INFINITY;
    for (int n = beg + t; n < end; n += 256) mx = fmaxf(mx, gate[n]);
    red[t] = mx;
    __syncthreads();
    for (int sft = 128; sft > 0; sft >>= 1) {
        if (t < sft) red[t] = fmaxf(red[t], red[t + sft]);
        __syncthreads();
    }
    if (t == 0) gmax_s = red[0];
    __syncthreads();
    float gm = gmax_s;
    int ln = t >> 5, o = t & 31;
    float acc = 0.f, den = 0.f;
    for (int n0 = beg; n0 < end; n0 += 8) {
        __syncthreads();
        for (int i = t; i < 8 * H; i += 256) {
            int r = i >> 6, c = i & 63;
            int n = n0 + r;
            hs[r][c] = (n < end) ? h[(size_t)n * H + c] : 0.f;
        }
        __syncthreads();
        int n = n0 + ln;
        if (n < end) {
            float wt = __expf(gate[n] - gm);
            float d0 = 0.f;
            #pragma unroll
            for (int i = 0; i < H; i++) d0 += hs[ln][i] * wls[i * OUTD + o];
            acc += wt * d0;
            if (o == 0) den += wt;
        }
    }
    __syncthreads();
    red[t] = acc;
    if (o == 0) den_s[ln] = den;
    __syncthreads();
    for (int sft = 4; sft >= 1; sft >>= 1) {
        if (ln < sft) red[t] += red[t + sft * 32];
        __syncthreads();
    }
    if (t == 0) {
        float dt = 0.f;
        #pragma unroll
        for (int i = 0; i < 8; i++) dt += den_s[i];
        den_tot = dt;
    }
    __syncthreads();
    if (ln == 0) {
        float dt = den_tot;
        out[g * OUTD + o] = (dt > 0.f) ? red[o] / dt + ob[o] : 0.f;
    }
}

extern "C" void kernel_launch(void* const* d_in, const int* in_sizes, int n_in,
                              void* d_out, int out_size, void* d_ws, size_t ws_size,
                              hipStream_t stream)
{
    const int* x        = (const int*)d_in[0];
    const int* ei       = (const int*)d_in[1];
    const int* ea       = (const int*)d_in[2];
    const int* batch    = (const int*)d_in[3];
    const float* node_emb = (const float*)d_in[4];
    const float* edge_emb = (const float*)d_in[5];
    const float* Wq    = (const float*)d_in[6];
    const float* Wk    = (const float*)d_in[7];
    const float* Wv    = (const float*)d_in[8];
    const float* We    = (const float*)d_in[9];
    const float* Wskip = (const float*)d_in[10];
    const float* bq    = (const float*)d_in[11];
    const float* bk    = (const float*)d_in[12];
    const float* bv    = (const float*)d_in[13];
    const float* bskip = (const float*)d_in[14];
    const float* gate_W = (const float*)d_in[15];
    const float* gate_b = (const float*)d_in[16];
    const float* out_W  = (const float*)d_in[17];
    const float* out_b  = (const float*)d_in[18];
    float* out = (float*)d_out;

    const size_t NH = (size_t)N_NODES * H;
    float* ws   = (float*)d_ws;
    float* h    = ws;                        // fp32 h, NH floats
    ushort_t* qs16 = (ushort_t*)(h + NH);    // bf16 [q(64)|s(64)] per node = NH floats of space
    unsigned* kv32 = (unsigned*)(h + 2 * NH); // packed bf16 k|v, 64 uints/node = NH floats of space
    float* te   = h + 3 * NH;
    float* gate = te + LAYERS * 10 * H;
    int* deg       = (int*)(gate + N_NODES);
    int* row_start = deg + N_NODES;
    int* cursor    = row_start + N_NODES;
    int* packed    = cursor + N_NODES;
    int* gs        = packed + N_EDGES;   // 257 ints
    int* bsum      = gs + NGRAPH + 1;    // 196

    hipMemsetAsync(deg, 0, N_NODES * sizeof(int), stream);

    k_front<<<NB_FRONT, 256, 0, stream>>>(x, node_emb, h, edge_emb, We, te, ei, deg, batch, gs);
    k_scan1<<<SCAN_NB, 256, 0, stream>>>(deg, bsum);
    k_scan23<<<SCAN_NB, 256, 0, stream>>>(deg, bsum, row_start, cursor);

    // layer 0: gemm fused with scatter (independent work, co-scheduled)
    k_gemm_scatter<<<NB_GEMM + NB_HIST, 256, 0, stream>>>(
        h, Wq, Wk, Wv, Wskip, bq, bk, bv, bskip, qs16, kv32, ei, ea, cursor, packed);
    k_agg<<<(N_NODES + 3) / 4, 256, 0, stream>>>(
        row_start, cursor, packed, qs16, kv32, te, h, nullptr, nullptr, nullptr);

    for (int l = 1; l < LAYERS; l++) {
        k_gemm<<<NB_GEMM, 256, 0, stream>>>(
            h,
            Wq + (size_t)l * H * H, Wk + (size_t)l * H * H,
            Wv + (size_t)l * H * H, Wskip + (size_t)l * H * H,
            bq + (size_t)l * H, bk + (size_t)l * H, bv + (size_t)l * H, bskip + (size_t)l * H,
            qs16, kv32);
        const float* gw = (l == LAYERS - 1) ? gate_W : nullptr;
        const float* gb = (l == LAYERS - 1) ? gate_b : nullptr;
        float* gp       = (l == LAYERS - 1) ? gate : nullptr;
        k_agg<<<(N_NODES + 3) / 4, 256, 0, stream>>>(
            row_start, cursor, packed, qs16, kv32, te + (size_t)l * 10 * H, h, gw, gb, gp);
    }

    k_readout2<<<NGRAPH, 256, 0, stream>>>(h, out_W, out_b, gate, gs, out);
}

// Round 17
// 452.772 us; speedup vs baseline: 1.0807x; 1.0580x over previous
//
#include <hip/hip_runtime.h>
#include <hip/hip_bf16.h>

#define N_NODES 50000
#define N_EDGES 800000
#define H 64
#define ED 32
#define LAYERS 3
#define NGRAPH 256
#define OUTD 32
#define SCALE 0.125f
#define SCAN_NB ((N_NODES + 255) / 256)   // 196

// fused front-end block ranges
#define NB_INIT 12500
#define NB_TE   8
#define NB_HIST 3125
#define NB_GB   2
#define NB_FRONT (NB_INIT + NB_TE + NB_HIST + NB_GB)
#define NB_GEMM ((N_NODES + 63) / 64)     // 782

typedef __attribute__((ext_vector_type(16))) float f16v;
typedef unsigned short ushort_t;

// fp32 -> bf16 round-to-nearest-even
__device__ __forceinline__ unsigned f2bf(float f) {
    unsigned u = __float_as_uint(f);
    return (u + 0x7FFFu + ((u >> 16) & 1u)) >> 16;
}

// ---------------- fused front end: init_h | te | hist | gbounds ----------------
__global__ __launch_bounds__(256) void k_front(
    const int* __restrict__ x, const float* __restrict__ node_emb, float* __restrict__ h,
    const float* __restrict__ edge_emb, const float* __restrict__ We, float* __restrict__ te,
    const int* __restrict__ ei, int* __restrict__ deg,
    const int* __restrict__ batch, int* __restrict__ gs)
{
    int b = blockIdx.x, t = threadIdx.x;
    if (b < NB_INIT) {
        int i = b * 256 + t;
        int n = i >> 6, c = i & 63;
        h[i] = node_emb[x[n] * H + c];
    } else if (b < NB_INIT + NB_TE) {
        int i = (b - NB_INIT) * 256 + t;
        if (i < LAYERS * 10 * H) {
            int c = i & 63;
            int cat = (i >> 6) % 10;
            int l = i / (10 * H);
            float acc = 0.f;
            for (int d = 0; d < ED; d++)
                acc += edge_emb[cat * ED + d] * We[((size_t)l * ED + d) * H + c];
            te[i] = acc;
        }
    } else if (b < NB_INIT + NB_TE + NB_HIST) {
        int e = (b - NB_INIT - NB_TE) * 256 + t;
        atomicAdd(&deg[ei[N_EDGES + e]], 1);
    } else {
        int g = (b - NB_INIT - NB_TE - NB_HIST) * 256 + t;
        if (g <= NGRAPH) {
            int lo = 0, hi = N_NODES;
            while (lo < hi) {
                int mid = (lo + hi) >> 1;
                if (batch[mid] < g) lo = mid + 1; else hi = mid;
            }
            gs[g] = lo;
        }
    }
}

// ---------------- scans ----------------
__global__ __launch_bounds__(256) void k_scan1(const int* __restrict__ deg, int* __restrict__ bsum) {
    __shared__ int red[256];
    int t = threadIdx.x;
    int i = blockIdx.x * 256 + t;
    red[t] = (i < N_NODES) ? deg[i] : 0;
    __syncthreads();
    for (int s = 128; s > 0; s >>= 1) {
        if (t < s) red[t] += red[t + s];
        __syncthreads();
    }
    if (t == 0) bsum[blockIdx.x] = red[0];
}

__global__ __launch_bounds__(256) void k_scan23(const int* __restrict__ deg, const int* __restrict__ bsum,
                                                int* __restrict__ row_start, int* __restrict__ cursor) {
    __shared__ int part[256];
    int t = threadIdx.x;
    part[t] = (t < SCAN_NB) ? bsum[t] : 0;
    __syncthreads();
    for (int off = 1; off < 256; off <<= 1) {
        int add = (t >= off) ? part[t - off] : 0;
        __syncthreads();
        part[t] += add;
        __syncthreads();
    }
    int boff = (blockIdx.x == 0) ? 0 : part[blockIdx.x - 1];
    __syncthreads();
    int i = blockIdx.x * 256 + t;
    int v = (i < N_NODES) ? deg[i] : 0;
    part[t] = v;
    __syncthreads();
    for (int off = 1; off < 256; off <<= 1) {
        int add = (t >= off) ? part[t - off] : 0;
        __syncthreads();
        part[t] += add;
        __syncthreads();
    }
    if (i < N_NODES) {
        int excl = part[t] - v + boff;
        row_start[i] = excl;
        cursor[i] = excl;
    }
}

// ---------------- gemm body: wave = matrix, lane = col (fp32 h via s_load) ----------------
// q -> bf16 qs16[n][0:64) (NT store); s -> bf16 qs16[n][64:128) (NT); k,v -> one uint
__device__ __forceinline__ void gemm_store(int wvi, int lane, int n, float acc,
                                           ushort_t* __restrict__ qs16, unsigned* __restrict__ kv32)
{
    if (wvi == 0)      __builtin_nontemporal_store((ushort_t)f2bf(acc), qs16 + (size_t)n * 128 + lane);
    else if (wvi == 3) __builtin_nontemporal_store((ushort_t)f2bf(acc), qs16 + (size_t)n * 128 + 64 + lane);
    else if (wvi == 1) ((ushort_t*)kv32)[(((size_t)n << 6) + lane) * 2 + 1] = (ushort_t)f2bf(acc);
    else               ((ushort_t*)kv32)[(((size_t)n << 6) + lane) * 2 + 0] = (ushort_t)f2bf(acc);
}

__device__ __forceinline__ void gemm_body(
    int bid, const float* __restrict__ h,
    const float* __restrict__ Wq, const float* __restrict__ Wk,
    const float* __restrict__ Wv, const float* __restrict__ Wsk,
    const float* __restrict__ bq, const float* __restrict__ bk,
    const float* __restrict__ bv, const float* __restrict__ bsk,
    ushort_t* __restrict__ qs16, unsigned* __restrict__ kv32)
{
    int wvi = threadIdx.x >> 6, lane = threadIdx.x & 63;
    const float* Wm = (wvi == 0) ? Wq : (wvi == 1) ? Wk : (wvi == 2) ? Wv : Wsk;
    const float* bm = (wvi == 0) ? bq : (wvi == 1) ? bk : (wvi == 2) ? bv : bsk;
    f16v w0, w1, w2, w3;
    #pragma unroll
    for (int i = 0; i < 16; i++) w0[i] = Wm[i * H + lane];
    #pragma unroll
    for (int i = 0; i < 16; i++) w1[i] = Wm[(16 + i) * H + lane];
    #pragma unroll
    for (int i = 0; i < 16; i++) w2[i] = Wm[(32 + i) * H + lane];
    #pragma unroll
    for (int i = 0; i < 16; i++) w3[i] = Wm[(48 + i) * H + lane];
    float bias = bm[lane];
    int base = bid * 64;
    int nEnd = min(base + 64, N_NODES);
    for (int n = base; n < nEnd; n++) {
        const float* hrow = h + (size_t)n * H;
        f16v h0, h1, h2, h3;
        asm volatile(
            "s_load_dwordx16 %0, %4, 0x0\n\t"
            "s_load_dwordx16 %1, %4, 0x40\n\t"
            "s_load_dwordx16 %2, %4, 0x80\n\t"
            "s_load_dwordx16 %3, %4, 0xc0\n\t"
            "s_waitcnt lgkmcnt(0)"
            : "=s"(h0), "=s"(h1), "=s"(h2), "=s"(h3)
            : "s"(hrow));
        float acc = bias;
        #pragma unroll
        for (int i = 0; i < 16; i++) acc = fmaf(h0[i], w0[i], acc);
        #pragma unroll
        for (int i = 0; i < 16; i++) acc = fmaf(h1[i], w1[i], acc);
        #pragma unroll
        for (int i = 0; i < 16; i++) acc = fmaf(h2[i], w2[i], acc);
        #pragma unroll
        for (int i = 0; i < 16; i++) acc = fmaf(h3[i], w3[i], acc);
        gemm_store(wvi, lane, n, acc, qs16, kv32);
    }
}

// layers 1,2: plain gemm
__global__ __launch_bounds__(256, 1) void k_gemm(
    const float* __restrict__ h,
    const float* __restrict__ Wq, const float* __restrict__ Wk,
    const float* __restrict__ Wv, const float* __restrict__ Wsk,
    const float* __restrict__ bq, const float* __restrict__ bk,
    const float* __restrict__ bv, const float* __restrict__ bsk,
    ushort_t* __restrict__ qs16, unsigned* __restrict__ kv32)
{
    gemm_body(blockIdx.x, h, Wq, Wk, Wv, Wsk, bq, bk, bv, bsk, qs16, kv32);
}

// layer 0: gemm blocks [0,NB_GEMM), scatter blocks [NB_GEMM, NB_GEMM+NB_HIST)
__global__ __launch_bounds__(256, 1) void k_gemm_scatter(
    const float* __restrict__ h,
    const float* __restrict__ Wq, const float* __restrict__ Wk,
    const float* __restrict__ Wv, const float* __restrict__ Wsk,
    const float* __restrict__ bq, const float* __restrict__ bk,
    const float* __restrict__ bv, const float* __restrict__ bsk,
    ushort_t* __restrict__ qs16, unsigned* __restrict__ kv32,
    const int* __restrict__ ei, const int* __restrict__ ea,
    int* __restrict__ cursor, int* __restrict__ packed)
{
    int b = blockIdx.x;
    if (b < NB_GEMM) {
        gemm_body(b, h, Wq, Wk, Wv, Wsk, bq, bk, bv, bsk, qs16, kv32);
    } else {
        int e = (b - NB_GEMM) * 256 + threadIdx.x;
        int src = ei[e], dst = ei[N_EDGES + e], cat = ea[e];
        int pos = atomicAdd(&cursor[dst], 1);
        packed[pos] = src | (cat << 16);
    }
}

// per-edge load bundle
struct EdgeLd { uint4 kv; float4 t; };
__device__ __forceinline__ EdgeLd edge_load(int pkt, const unsigned* __restrict__ kv32,
                                            const float* tel, int i16) {
    EdgeLd r;
    r.kv = *(const uint4*)(kv32 + ((size_t)(pkt & 0xFFFF) << 6) + (i16 << 2));
    r.t  = *(const float4*)(tel + ((pkt >> 16) << 6) + (i16 << 2));
    return r;
}
__device__ __forceinline__ float edge_dot(const EdgeLd& e, const float4& q4) {
    float p;
    p = (__uint_as_float(e.kv.x & 0xFFFF0000u) + e.t.x) * q4.x;
    p = fmaf(__uint_as_float(e.kv.y & 0xFFFF0000u) + e.t.y, q4.y, p);
    p = fmaf(__uint_as_float(e.kv.z & 0xFFFF0000u) + e.t.z, q4.z, p);
    p = fmaf(__uint_as_float(e.kv.w & 0xFFFF0000u) + e.t.w, q4.w, p);
    p += __shfl_xor(p, 1); p += __shfl_xor(p, 2);
    p += __shfl_xor(p, 4); p += __shfl_xor(p, 8);
    return p * SCALE;
}
__device__ __forceinline__ float4 edge_val(const EdgeLd& e) {
    float4 v;
    v.x = __uint_as_float(e.kv.x << 16) + e.t.x;
    v.y = __uint_as_float(e.kv.y << 16) + e.t.y;
    v.z = __uint_as_float(e.kv.z << 16) + e.t.z;
    v.w = __uint_as_float(e.kv.w << 16) + e.t.w;
    return v;
}

// ---------------- fused gather v4: one dst per 16-lane group (4 dsts/wave) -------------
// 4-deep unroll engages for deg >= 4 (~all dsts); no cross-group merge needed.
__global__ __launch_bounds__(256) void k_agg(
    const int* __restrict__ row_start, const int* __restrict__ row_end,
    const int* __restrict__ packed,
    const ushort_t* __restrict__ qs16, const unsigned* __restrict__ kv32,
    const float* __restrict__ te, float* __restrict__ h,
    const float* __restrict__ gW, const float* __restrict__ gb, float* __restrict__ gate)
{
    __shared__ float tel[10 * 64];
    int t = threadIdx.x;
    int wave = t >> 6, lane = t & 63;
    int g = lane >> 4, i16 = lane & 15;
    int dst = blockIdx.x * 16 + wave * 4 + g;
    bool active = dst < N_NODES;
    int beg = 0, end = 0;
    uint2 qw = {0u, 0u};
    if (active) {
        beg = row_start[dst];
        end = row_end[dst];
        qw = *(const uint2*)(qs16 + (size_t)dst * 128 + (i16 << 2));   // issue before barrier
    }
    for (int i = t; i < 10 * 64; i += 256) tel[i] = te[i];
    __syncthreads();
    float4 q4;
    q4.x = __uint_as_float(qw.x << 16);
    q4.y = __uint_as_float(qw.x & 0xFFFF0000u);
    q4.z = __uint_as_float(qw.y << 16);
    q4.w = __uint_as_float(qw.y & 0xFFFF0000u);
    float m = -1e30f, l = 0.f;
    float4 acc = {0.f, 0.f, 0.f, 0.f};
    int e = beg;
    for (; e + 3 < end; e += 4) {
        int p0 = packed[e], p1 = packed[e + 1], p2 = packed[e + 2], p3 = packed[e + 3];
        EdgeLd e0 = edge_load(p0, kv32, tel, i16);
        EdgeLd e1 = edge_load(p1, kv32, tel, i16);
        EdgeLd e2 = edge_load(p2, kv32, tel, i16);
        EdgeLd e3 = edge_load(p3, kv32, tel, i16);
        float a0 = edge_dot(e0, q4), a1 = edge_dot(e1, q4);
        float a2 = edge_dot(e2, q4), a3 = edge_dot(e3, q4);
        float mn = fmaxf(m, fmaxf(fmaxf(a0, a1), fmaxf(a2, a3)));
        float corr = __expf(m - mn);
        float w0 = __expf(a0 - mn), w1 = __expf(a1 - mn);
        float w2 = __expf(a2 - mn), w3 = __expf(a3 - mn);
        float4 v0 = edge_val(e0), v1 = edge_val(e1), v2 = edge_val(e2), v3 = edge_val(e3);
        acc.x = fmaf(w0, v0.x, fmaf(w1, v1.x, fmaf(w2, v2.x, fmaf(w3, v3.x, acc.x * corr))));
        acc.y = fmaf(w0, v0.y, fmaf(w1, v1.y, fmaf(w2, v2.y, fmaf(w3, v3.y, acc.y * corr))));
        acc.z = fmaf(w0, v0.z, fmaf(w1, v1.z, fmaf(w2, v2.z, fmaf(w3, v3.z, acc.z * corr))));
        acc.w = fmaf(w0, v0.w, fmaf(w1, v1.w, fmaf(w2, v2.w, fmaf(w3, v3.w, acc.w * corr))));
        l = fmaf(l, corr, (w0 + w1) + (w2 + w3));
        m = mn;
    }
    for (; e < end; e++) {
        int pkt = packed[e];
        EdgeLd e0 = edge_load(pkt, kv32, tel, i16);
        float a = edge_dot(e0, q4);
        float mn = fmaxf(m, a);
        float corr = __expf(m - mn);
        float w = __expf(a - mn);
        float4 v4 = edge_val(e0);
        acc.x = fmaf(w, v4.x, acc.x * corr);
        acc.y = fmaf(w, v4.y, acc.y * corr);
        acc.z = fmaf(w, v4.z, acc.z * corr);
        acc.w = fmaf(w, v4.w, acc.w * corr);
        l = fmaf(l, corr, w);
        m = mn;
    }
    float inv = (l > 0.f) ? 1.f / l : 0.f;
    uint2 sw = {0u, 0u};
    if (active) sw = *(const uint2*)(qs16 + (size_t)dst * 128 + 64 + (i16 << 2));
    float4 s4;
    s4.x = __uint_as_float(sw.x << 16);
    s4.y = __uint_as_float(sw.x & 0xFFFF0000u);
    s4.z = __uint_as_float(sw.y << 16);
    s4.w = __uint_as_float(sw.y & 0xFFFF0000u);
    float4 hv;
    hv.x = fmaxf(acc.x * inv + s4.x, 0.f);
    hv.y = fmaxf(acc.y * inv + s4.y, 0.f);
    hv.z = fmaxf(acc.z * inv + s4.z, 0.f);
    hv.w = fmaxf(acc.w * inv + s4.w, 0.f);
    if (active) *(float4*)(h + (size_t)dst * H + (i16 << 2)) = hv;
    if (gW && active) {   // fused readout gate (final layer only)
        float4 g4 = *(const float4*)(gW + (i16 << 2));
        float p = hv.x * g4.x + hv.y * g4.y + hv.z * g4.z + hv.w * g4.w;
        p += __shfl_xor(p, 1); p += __shfl_xor(p, 2);
        p += __shfl_xor(p, 4); p += __shfl_xor(p, 8);
        if (i16 == 0) gate[dst] = p + gb[0];
    }
}

// ---------------- fused per-graph readout ----------------
__global__ __launch_bounds__(256) void k_readout2(
    const float* __restrict__ h, const float* __restrict__ oW,
    const float* __restrict__ ob, const float* __restrict__ gate,
    const int* __restrict__ gs, float* __restrict__ out)
{
    __shared__ float wls[H * OUTD];
    __shared__ float hs[8][H + 1];
    __shared__ float red[256];
    __shared__ float den_s[8];
    __shared__ float gmax_s, den_tot;
    int t = threadIdx.x;
    int g = blockIdx.x;
    for (int i = t; i < H * OUTD; i += 256) wls[i] = oW[i];
    int beg = gs[g], end = gs[g + 1];
    float mx = -INFINITY;
    for (int n = beg + t; n < end; n += 256) mx = fmaxf(mx, gate[n]);
    red[t] = mx;
    __syncthreads();
    for (int sft = 128; sft > 0; sft >>= 1) {
        if (t < sft) red[t] = fmaxf(red[t], red[t + sft]);
        __syncthreads();
    }
    if (t == 0) gmax_s = red[0];
    __syncthreads();
    float gm = gmax_s;
    int ln = t >> 5, o = t & 31;
    float acc = 0.f, den = 0.f;
    for (int n0 = beg; n0 < end; n0 += 8) {
        __syncthreads();
        for (int i = t; i < 8 * H; i += 256) {
            int r = i >> 6, c = i & 63;
            int n = n0 + r;
            hs[r][c] = (n < end) ? h[(size_t)n * H + c] : 0.f;
        }
        __syncthreads();
        int n = n0 + ln;
        if (n < end) {
            float wt = __expf(gate[n] - gm);
            float d0 = 0.f;
            #pragma unroll
            for (int i = 0; i < H; i++) d0 += hs[ln][i] * wls[i * OUTD + o];
            acc += wt * d0;
            if (o == 0) den += wt;
        }
    }
    __syncthreads();
    red[t] = acc;
    if (o == 0) den_s[ln] = den;
    __syncthreads();
    for (int sft = 4; sft >= 1; sft >>= 1) {
        if (ln < sft) red[t] += red[t + sft * 32];
        __syncthreads();
    }
    if (t == 0) {
        float dt = 0.f;
        #pragma unroll
        for (int i = 0; i < 8; i++) dt += den_s[i];
        den_tot = dt;
    }
    __syncthreads();
    if (ln == 0) {
        float dt = den_tot;
        out[g * OUTD + o] = (dt > 0.f) ? red[o] / dt + ob[o] : 0.f;
    }
}

extern "C" void kernel_launch(void* const* d_in, const int* in_sizes, int n_in,
                              void* d_out, int out_size, void* d_ws, size_t ws_size,
                              hipStream_t stream)
{
    const int* x        = (const int*)d_in[0];
    const int* ei       = (const int*)d_in[1];
    const int* ea       = (const int*)d_in[2];
    const int* batch    = (const int*)d_in[3];
    const float* node_emb = (const float*)d_in[4];
    const float* edge_emb = (const float*)d_in[5];
    const float* Wq    = (const float*)d_in[6];
    const float* Wk    = (const float*)d_in[7];
    const float* Wv    = (const float*)d_in[8];
    const float* We    = (const float*)d_in[9];
    const float* Wskip = (const float*)d_in[10];
    const float* bq    = (const float*)d_in[11];
    const float* bk    = (const float*)d_in[12];
    const float* bv    = (const float*)d_in[13];
    const float* bskip = (const float*)d_in[14];
    const float* gate_W = (const float*)d_in[15];
    const float* gate_b = (const float*)d_in[16];
    const float* out_W  = (const float*)d_in[17];
    const float* out_b  = (const float*)d_in[18];
    float* out = (float*)d_out;

    const size_t NH = (size_t)N_NODES * H;
    float* ws   = (float*)d_ws;
    float* h    = ws;                        // fp32 h, NH floats
    ushort_t* qs16 = (ushort_t*)(h + NH);    // bf16 [q(64)|s(64)] per node
    unsigned* kv32 = (unsigned*)(h + 2 * NH); // packed bf16 k|v, 64 uints/node
    float* te   = h + 3 * NH;
    float* gate = te + LAYERS * 10 * H;
    int* deg       = (int*)(gate + N_NODES);
    int* row_start = deg + N_NODES;
    int* cursor    = row_start + N_NODES;
    int* packed    = cursor + N_NODES;
    int* gs        = packed + N_EDGES;   // 257 ints
    int* bsum      = gs + NGRAPH + 1;    // 196

    hipMemsetAsync(deg, 0, N_NODES * sizeof(int), stream);

    k_front<<<NB_FRONT, 256, 0, stream>>>(x, node_emb, h, edge_emb, We, te, ei, deg, batch, gs);
    k_scan1<<<SCAN_NB, 256, 0, stream>>>(deg, bsum);
    k_scan23<<<SCAN_NB, 256, 0, stream>>>(deg, bsum, row_start, cursor);

    // layer 0: gemm fused with scatter (independent work, co-scheduled)
    k_gemm_scatter<<<NB_GEMM + NB_HIST, 256, 0, stream>>>(
        h, Wq, Wk, Wv, Wskip, bq, bk, bv, bskip, qs16, kv32, ei, ea, cursor, packed);
    k_agg<<<(N_NODES + 15) / 16, 256, 0, stream>>>(
        row_start, cursor, packed, qs16, kv32, te, h, nullptr, nullptr, nullptr);

    for (int l = 1; l < LAYERS; l++) {
        k_gemm<<<NB_GEMM, 256, 0, stream>>>(
            h,
            Wq + (size_t)l * H * H, Wk + (size_t)l * H * H,
            Wv + (size_t)l * H * H, Wskip + (size_t)l * H * H,
            bq + (size_t)l * H, bk + (size_t)l * H, bv + (size_t)l * H, bskip + (size_t)l * H,
            qs16, kv32);
        const float* gw = (l == LAYERS - 1) ? gate_W : nullptr;
        const float* gb = (l == LAYERS - 1) ? gate_b : nullptr;
        float* gp       = (l == LAYERS - 1) ? gate : nullptr;
        k_agg<<<(N_NODES + 15) / 16, 256, 0, stream>>>(
            row_start, cursor, packed, qs16, kv32, te + (size_t)l * 10 * H, h, gw, gb, gp);
    }

    k_readout2<<<NGRAPH, 256, 0, stream>>>(h, out_W, out_b, gate, gs, out);
}